// Round 6
// baseline (3669.640 us; speedup 1.0000x reference)
//
#include <hip/hip_runtime.h>
#include <hip/hip_bf16.h>

#define EE 256
#define SS 16
#define MM 16
#define GG 32000
#define NSTEP 128
#define ROWS 4096
#define VSPLIT 8

// ---------- workspace layout (bytes), lifetimes overlapped ----------
#define OFF_ZSF  0u
#define OFF_TAIL 4194304u
#define OFF_ZF   (OFF_TAIL + 0u)        // f64 32x256 = 65536
#define OFF_ZN   (OFF_TAIL + 65536u)    // f64 32x256 = 65536
#define OFF_EM   (OFF_TAIL + 131072u)   // f64 32x256 = 65536
#define OFF_A2   (OFF_TAIL + 196608u)   // f64 32x16  = 4096
#define OFF_PS   (OFF_TAIL + 0u)        // f32 8x4096 = 131072  (phase B overlap)
#define OFF_PT   (OFF_TAIL + 131072u)   // f32 8x4096 = 131072
#define OFF_FLAG (OFF_TAIL + 262144u)   // int flag
#define WS_REQ   (OFF_TAIL + 266240u)   // 4,460,544 B

__device__ __forceinline__ double wredd(double v){
    #pragma unroll
    for (int m = 1; m < 64; m <<= 1) v += __shfl_xor(v, m);
    return v;
}

// dtype-flexible index read: int64 (little-endian low word) or int32
__device__ __forceinline__ int idx_at(const int* __restrict__ p, int i, int is64){
    return is64 ? p[2*i] : p[i];
}

__global__ __launch_bounds__(256) void k_sentinel(float* __restrict__ outp, float val){
    int r = blockIdx.x * 256 + threadIdx.x;
    outp[r] = val;
}

// ---------------- K-1: detect index dtype (int64 vs int32) ----------------
__global__ void k_detect(const int* __restrict__ zi, int* __restrict__ flag){
    if (threadIdx.x == 0 && blockIdx.x == 0){
        bool odd_zero = true, even_ok = true;
        for (int i = 0; i < 16; ++i){
            int lo = zi[2*i], hi = zi[2*i+1];
            if (hi != 0) odd_zero = false;
            if (lo < 0 || lo >= 8192) even_ok = false;
        }
        flag[0] = (odd_zero && even_ok) ? 1 : 0;
    }
}

// ---------------- K0: gather z rows (f32 -> f64, exact) ----------------
__global__ __launch_bounds__(256) void k_init(const float* __restrict__ latent,
                                              const int* __restrict__ zi,
                                              const int* __restrict__ flag,
                                              double* __restrict__ zf)
{
    int b = blockIdx.x, t = threadIdx.x;
    int zb = idx_at(zi, b, flag[0]);
    zf[b*EE + t] = (double)latent[(size_t)zb * 8192 + t];
}

// ---------------- K1: f64 norm + att + att2 + emit ----------------
__global__ __launch_bounds__(256) void k_step1(const float* __restrict__ latent,
                                               const int* __restrict__ zi,
                                               const int* __restrict__ flag,
                                               const float* __restrict__ anchor_w,
                                               const float* __restrict__ anchor_b,
                                               const double* __restrict__ zf,
                                               double* __restrict__ znf,
                                               double* __restrict__ emitf,
                                               double* __restrict__ att2f,
                                               float* __restrict__ zsf,
                                               int step)
{
    int b = blockIdx.x, t = threadIdx.x;
    __shared__ double zl[EE];
    __shared__ double l1[SS], l2[MM];
    __shared__ double rbuf[8];

    int zb = idx_at(zi, b, flag[0]);
    const float* base = latent + (size_t)zb * 8192;  // xk=base[0:4096]*100, xv=base[4096:]*100

    double zv = zf[b*EE + t];
    double s1 = wredd(zv);
    double s2 = wredd(zv * zv);
    int wave = t >> 6;
    if ((t & 63) == 0){ rbuf[wave] = s1; rbuf[4+wave] = s2; }
    __syncthreads();
    double tot1 = rbuf[0]+rbuf[1]+rbuf[2]+rbuf[3];
    double tot2 = rbuf[4]+rbuf[5]+rbuf[6]+rbuf[7];
    double mean = tot1 * (1.0/EE);
    double var  = (tot2 - (double)EE*mean*mean) * (1.0/(EE-1));
    var = var > 0.0 ? var : 0.0;
    double sc = 0.113 / (1e-5 + sqrt(var));
    double zn = zv * sc;
    zl[t] = zn;
    znf[b*EE + t] = zn;
    __syncthreads();

    // l1[s] = 100*(zn . base_s), l2[s] = zn . anchor_w[s] + anchor_b[s]
    int sidx = t >> 4, lane16 = t & 15;
    const float* xks = base + sidx*EE;
    const float* aws = anchor_w + (size_t)sidx*EE;
    double p1 = 0.0, p2 = 0.0;
    #pragma unroll
    for (int c = 0; c < 16; ++c){
        int k = lane16*16 + c;
        double z = zl[k];
        p1 += z * (double)xks[k];
        p2 += z * (double)aws[k];
    }
    #pragma unroll
    for (int m = 1; m < 16; m <<= 1){ p1 += __shfl_xor(p1, m); p2 += __shfl_xor(p2, m); }
    if (lane16 == 0){ l1[sidx] = p1 * 100.0; l2[sidx] = p2 + (double)anchor_b[sidx]; }
    __syncthreads();

    double mx1 = -1e300, mx2 = -1e300;
    #pragma unroll
    for (int s = 0; s < 16; ++s){ mx1 = fmax(mx1, l1[s]); mx2 = fmax(mx2, l2[s]); }
    double att[16]; double sum1 = 0.0, sum2 = 0.0;
    #pragma unroll
    for (int s = 0; s < 16; ++s){
        att[s] = exp(l1[s] - mx1); sum1 += att[s];
        sum2  += exp(l2[s] - mx2);
    }
    double inv1 = 1.0 / sum1;
    if (t < 16) att2f[b*16 + t] = exp(l2[t] - mx2) / sum2;

    const float* xvb = base + 4096;
    double em = 0.0;
    #pragma unroll
    for (int s = 0; s < 16; ++s) em += (att[s] * inv1) * (double)xvb[s*EE + t];
    em *= 100.0;
    emitf[b*EE + t] = em;
    zsf[((size_t)b * NSTEP + step) * EE + t] = (float)em;
}

// ---------------- K2: f64 mixed2 GEMM + z update (one e-column per WG) -------
__global__ __launch_bounds__(256) void k_step2(const float* __restrict__ W,
                                               const float* __restrict__ tb,
                                               const double* __restrict__ znf,
                                               const double* __restrict__ att2f,
                                               const double* __restrict__ emitf,
                                               double* __restrict__ zf)
{
    int e = blockIdx.x, t = threadIdx.x;
    __shared__ double wl[16][257];
    __shared__ double znl[32][257];
    __shared__ double red[8][33];

    #pragma unroll
    for (int m = 0; m < 16; ++m) wl[m][t] = (double)W[((size_t)(m*EE + e)) * EE + t];
    #pragma unroll
    for (int b = 0; b < 32; ++b) znl[b][t] = znf[b*EE + t];
    __syncthreads();

    int b = t & 31, g = t >> 5;      // g in 0..7, m = {g, g+8}
    double acc0 = 0.0, acc1 = 0.0;
    #pragma unroll 4
    for (int k = 0; k < EE; ++k){
        double z = znl[b][k];
        acc0 += z * wl[g][k];
        acc1 += z * wl[g+8][k];
    }
    double a0 = att2f[b*16 + g], a1 = att2f[b*16 + g + 8];
    red[g][b] = a0 * (acc0 + (double)tb[g*EE + e]) + a1 * (acc1 + (double)tb[(g+8)*EE + e]);
    __syncthreads();

    if (t < 32){
        double dz = 0.0;
        #pragma unroll
        for (int gg = 0; gg < 8; ++gg) dz += red[gg][t];
        zf[t*EE + e] = znl[t][e] + dz + emitf[t*EE + e];
    }
}

// ---------------- K3: f32 vocab logits + streaming sumexp + target ----------
__global__ __launch_bounds__(256) void k_vocab_valu(const float* __restrict__ vw,
                                                    const float* __restrict__ vbias,
                                                    const float* __restrict__ zsf,
                                                    const int* __restrict__ y,
                                                    const int* __restrict__ flag,
                                                    float* __restrict__ pS,
                                                    float* __restrict__ pT)
{
    int rowgrp = blockIdx.x;    // rows [rowgrp*32, +32)
    int vs     = blockIdx.y;    // vocab [vs*4000, +4000)
    int t = threadIdx.x;

    __shared__ float zl[32][256];
    __shared__ int   yl[32];
    __shared__ float rs[4][32], rt[4][32];

    #pragma unroll
    for (int r = 0; r < 32; ++r) zl[r][t] = zsf[(size_t)(rowgrp*32 + r) * EE + t];
    if (t < 32) yl[t] = idx_at(y, rowgrp*32 + t, flag[0]);
    __syncthreads();

    float sums[32], targ[32];
    #pragma unroll
    for (int r = 0; r < 32; ++r){ sums[r] = 0.f; targ[r] = 0.f; }

    for (int p = t; p < 2000; p += 256){
        int n0 = vs*4000 + 2*p, n1 = n0 + 1;
        const float* w0 = vw + (size_t)n0 * EE;
        const float* w1 = w0 + EE;
        float acc0[32], acc1[32];
        #pragma unroll
        for (int r = 0; r < 32; ++r){ acc0[r] = 0.f; acc1[r] = 0.f; }
        for (int k = 0; k < EE; k += 4){
            float4 a = *(const float4*)&w0[k];
            float4 c = *(const float4*)&w1[k];
            #pragma unroll
            for (int r = 0; r < 32; ++r){
                float4 z = *(const float4*)&zl[r][k];
                acc0[r] += z.x*a.x + z.y*a.y + z.z*a.z + z.w*a.w;
                acc1[r] += z.x*c.x + z.y*c.y + z.z*c.z + z.w*c.w;
            }
        }
        float b0 = vbias[n0], b1 = vbias[n1];
        #pragma unroll
        for (int r = 0; r < 32; ++r){
            float v0 = acc0[r] + b0, v1 = acc1[r] + b1;
            sums[r] += expf(v0) + expf(v1);
            if (n0 == yl[r]) targ[r] += v0;
            if (n1 == yl[r]) targ[r] += v1;
        }
    }

    int wv = t >> 6, ln = t & 63;
    #pragma unroll
    for (int r = 0; r < 32; ++r){
        float s = sums[r], g = targ[r];
        #pragma unroll
        for (int m = 1; m < 64; m <<= 1){ s += __shfl_xor(s, m); g += __shfl_xor(g, m); }
        if (ln == 0){ rs[wv][r] = s; rt[wv][r] = g; }
    }
    __syncthreads();
    if (t < 32){
        float s = rs[0][t] + rs[1][t] + rs[2][t] + rs[3][t];
        float g = rt[0][t] + rt[1][t] + rt[2][t] + rt[3][t];
        int r = rowgrp*32 + t;
        pS[(size_t)vs*ROWS + r] = s;
        pT[(size_t)vs*ROWS + r] = g;
    }
}

// ---------------- K4: merge + FLOAT32 out ----------------
__global__ __launch_bounds__(256) void k_final(const float* __restrict__ pS,
                                               const float* __restrict__ pT,
                                               float* __restrict__ outp)
{
    int r = blockIdx.x * 256 + threadIdx.x;
    float s = 0.f, g = 0.f;
    #pragma unroll
    for (int i = 0; i < VSPLIT; ++i){ s += pS[(size_t)i*ROWS + r]; g += pT[(size_t)i*ROWS + r]; }
    outp[r] = g - logf(s);
}

extern "C" void kernel_launch(void* const* d_in, const int* in_sizes, int n_in,
                              void* d_out, int out_size, void* d_ws, size_t ws_size,
                              hipStream_t stream)
{
    (void)out_size;
    const float* latent   = (const float*)d_in[0];
    const float* trans_w  = (const float*)d_in[1];
    const float* trans_b  = (const float*)d_in[2];
    const float* anchor_w = (const float*)d_in[3];
    const float* anchor_b = (const float*)d_in[4];
    const float* vocab_w  = (const float*)d_in[5];
    const float* vocab_b  = (const float*)d_in[6];
    const int*   zi       = (const int*)d_in[7];
    const int*   y        = (const int*)d_in[8];

    float* outp = (float*)d_out;   // reference output dtype is FLOAT32

    if (ws_size < (size_t)WS_REQ){ k_sentinel<<<16, 256, 0, stream>>>(outp, 2000.0f); return; }
    {
        bool ok = (n_in >= 9)
               && in_sizes[0] == 67108864 && in_sizes[1] == 1048576
               && in_sizes[2] == 4096     && in_sizes[3] == 4096
               && in_sizes[4] == 16       && in_sizes[5] == 8192000
               && in_sizes[6] == 32000
               && (in_sizes[7] == 32   || in_sizes[7] == 64)
               && (in_sizes[8] == 4096 || in_sizes[8] == 8192);
        if (!ok){ k_sentinel<<<16, 256, 0, stream>>>(outp, 2100.0f); return; }
    }

    char* ws = (char*)d_ws;
    float*  zsf   = (float*)(ws + OFF_ZSF);
    double* zf    = (double*)(ws + OFF_ZF);
    double* znf   = (double*)(ws + OFF_ZN);
    double* emitf = (double*)(ws + OFF_EM);
    double* att2f = (double*)(ws + OFF_A2);
    float*  pS    = (float*)(ws + OFF_PS);
    float*  pT    = (float*)(ws + OFF_PT);
    int*    flag  = (int*)(ws + OFF_FLAG);

    k_detect<<<1, 64, 0, stream>>>(zi, flag);
    k_init<<<32, 256, 0, stream>>>(latent, zi, flag, zf);

    for (int stp = 0; stp < NSTEP; ++stp){
        k_step1<<<32, 256, 0, stream>>>(latent, zi, flag, anchor_w, anchor_b,
                                        zf, znf, emitf, att2f, zsf, stp);
        if (stp < NSTEP-1)
            k_step2<<<256, 256, 0, stream>>>(trans_w, trans_b, znf, att2f, emitf, zf);
    }

    k_vocab_valu<<<dim3(128, VSPLIT), 256, 0, stream>>>(vocab_w, vocab_b, zsf, y, flag, pS, pT);
    k_final<<<16, 256, 0, stream>>>(pS, pT, outp);
}